// Round 1
// baseline (1906.359 us; speedup 1.0000x reference)
//
#include <hip/hip_runtime.h>

typedef unsigned short u16;
typedef __bf16 bf16x8 __attribute__((ext_vector_type(8)));
typedef float  f32x4  __attribute__((ext_vector_type(4)));
typedef unsigned short u16x8 __attribute__((ext_vector_type(8)));

#define NB 32
#define NN 4096
#define ND 256
#define NS 11
#define NH 256
#define NM 512

__device__ __forceinline__ u16 f2bf(float f) {
  unsigned u = __float_as_uint(f);
  u += 0x7FFF + ((u >> 16) & 1);      // RNE; inputs are finite
  return (u16)(u >> 16);
}
__device__ __forceinline__ float bf2f(u16 h) {
  return __uint_as_float(((unsigned)h) << 16);
}

// ---------------- per-row mean / rstd of inputs (one wave per row) ----------
__global__ void k_stats(const float* __restrict__ x, float2* __restrict__ mu_rs) {
  int lane = threadIdx.x & 63;
  int wid  = threadIdx.x >> 6;
  int row  = blockIdx.x * 4 + wid;
  float4 v = *(const float4*)(x + (size_t)row * 256 + lane * 4);
  float s1 = v.x + v.y + v.z + v.w;
  float s2 = v.x*v.x + v.y*v.y + v.z*v.z + v.w*v.w;
#pragma unroll
  for (int off = 32; off; off >>= 1) { s1 += __shfl_xor(s1, off); s2 += __shfl_xor(s2, off); }
  if (lane == 0) {
    float mu  = s1 * (1.f/256.f);
    float var = s2 * (1.f/256.f) - mu*mu;
    mu_rs[row] = make_float2(mu, rsqrtf(var + 1e-5f));
  }
}

// ---------------- Wk|Wv -> transposed bf16 wT[512][256] --------------------
__global__ void k_cvt_w(const float* __restrict__ Wk, const float* __restrict__ Wv,
                        u16* __restrict__ wT) {
  int c = blockIdx.x;           // output column 0..511
  int t = threadIdx.x;          // k 0..255
  const float* src = (c < 256) ? Wk : Wv;
  int cc = c & 255;
  wT[c * 256 + t] = f2bf(src[t * 256 + cc]);
}

// ---------------- slots init ----------------------------------------------
__global__ void k_slots_init(const float* __restrict__ noise, const float* __restrict__ mu,
                             const float* __restrict__ ls, float* __restrict__ slots) {
  int row = blockIdx.x, t = threadIdx.x;
  slots[row*256 + t] = mu[t] + expf(ls[t]) * noise[row*256 + t];
}

// ---------------- fused LN + bf16 MFMA GEMM: kv = LN(x) @ [Wk|Wv] ----------
// 128x128 tile, 4 waves each 64x64 (m93-style), K=256 in 4 chunks of 64.
__global__ __launch_bounds__(256)
void k_gemm_kv(const float* __restrict__ x, const float2* __restrict__ mu_rs,
               const float* __restrict__ lnsc, const float* __restrict__ lnof,
               const u16* __restrict__ wT, u16* __restrict__ kv) {
  __shared__ __align__(16) u16 Al[128][72];   // pad 64->72 (+16B) breaks bank aliasing
  __shared__ __align__(16) u16 Bl[128][72];   // B^T layout: [col][k]
  __shared__ float scl[256], ofl[256];
  int t = threadIdx.x;
  scl[t] = lnsc[t]; ofl[t] = lnof[t];
  int row0 = blockIdx.y * 128;
  int col0 = blockIdx.x * 128;
  int srow = t >> 1, shalf = t & 1;           // staging: 2 threads per row, 32 elems each
  float2 mr = mu_rs[row0 + srow];
  int lane = t & 63, w = t >> 6;
  int wm = (w & 1) * 64, wn = (w >> 1) * 64;
  int fr = lane & 15;                         // frag m/n index
  int kq = (lane >> 4) * 8;                   // frag k offset
  f32x4 acc[4][4] = {};
  for (int kc = 0; kc < 256; kc += 64) {
    __syncthreads();
    { // stage A with LN applied, cast to bf16
      const float* xp = x + (size_t)(row0 + srow) * 256 + kc + shalf * 32;
#pragma unroll
      for (int g = 0; g < 4; ++g) {
        float4 f0 = *(const float4*)(xp + g*8);
        float4 f1 = *(const float4*)(xp + g*8 + 4);
        int kb = kc + shalf*32 + g*8;
        u16x8 o;
        o[0] = f2bf((f0.x - mr.x)*mr.y*scl[kb+0] + ofl[kb+0]);
        o[1] = f2bf((f0.y - mr.x)*mr.y*scl[kb+1] + ofl[kb+1]);
        o[2] = f2bf((f0.z - mr.x)*mr.y*scl[kb+2] + ofl[kb+2]);
        o[3] = f2bf((f0.w - mr.x)*mr.y*scl[kb+3] + ofl[kb+3]);
        o[4] = f2bf((f1.x - mr.x)*mr.y*scl[kb+4] + ofl[kb+4]);
        o[5] = f2bf((f1.y - mr.x)*mr.y*scl[kb+5] + ofl[kb+5]);
        o[6] = f2bf((f1.z - mr.x)*mr.y*scl[kb+6] + ofl[kb+6]);
        o[7] = f2bf((f1.w - mr.x)*mr.y*scl[kb+7] + ofl[kb+7]);
        *(u16x8*)&Al[srow][shalf*32 + g*8] = o;
      }
      const u16* wp = wT + (size_t)(col0 + srow) * 256 + kc + shalf*32;
#pragma unroll
      for (int g = 0; g < 4; ++g)
        *(u16x8*)&Bl[srow][shalf*32 + g*8] = *(const u16x8*)(wp + g*8);
    }
    __syncthreads();
#pragma unroll
    for (int ks = 0; ks < 2; ++ks) {
      int kk = ks*32 + kq;
      bf16x8 af[4], bf[4];
#pragma unroll
      for (int i = 0; i < 4; ++i) af[i] = *(const bf16x8*)&Al[wm + i*16 + fr][kk];
#pragma unroll
      for (int i = 0; i < 4; ++i) bf[i] = *(const bf16x8*)&Bl[wn + i*16 + fr][kk];
#pragma unroll
      for (int im = 0; im < 4; ++im)
#pragma unroll
        for (int in = 0; in < 4; ++in)
          acc[im][in] = __builtin_amdgcn_mfma_f32_16x16x32_bf16(af[im], bf[in], acc[im][in], 0, 0, 0);
    }
  }
  // epilogue: D mapping col=lane&15, row=(lane>>4)*4+r  [measured m89/m91]
  int r4 = (lane >> 4) * 4;
#pragma unroll
  for (int im = 0; im < 4; ++im)
#pragma unroll
    for (int in = 0; in < 4; ++in) {
      int gcol = col0 + wn + in*16 + fr;
#pragma unroll
      for (int r = 0; r < 4; ++r) {
        int grow = row0 + wm + im*16 + r4 + r;
        kv[(size_t)grow * 512 + gcol] = f2bf(acc[im][in][r]);
      }
    }
}

// ---------------- q = LN(slots) @ Wq * H^-0.5; also zero updates/colsum ----
__global__ void k_q_ln(const float* __restrict__ slots, const float* __restrict__ sc,
                       const float* __restrict__ of, const float* __restrict__ Wq,
                       float* __restrict__ q, float* __restrict__ updates,
                       float* __restrict__ colsum) {
  __shared__ float xn[256];
  __shared__ float red[8];
  int row = blockIdx.x, t = threadIdx.x;
  float v = slots[row*256 + t];
  float s1 = v, s2 = v*v;
#pragma unroll
  for (int off = 32; off; off >>= 1) { s1 += __shfl_xor(s1, off); s2 += __shfl_xor(s2, off); }
  int w = t >> 6;
  if ((t & 63) == 0) { red[w*2] = s1; red[w*2+1] = s2; }
  __syncthreads();
  float a1 = red[0] + red[2] + red[4] + red[6];
  float a2 = red[1] + red[3] + red[5] + red[7];
  float mu = a1 * (1.f/256.f);
  float rs = rsqrtf(a2 * (1.f/256.f) - mu*mu + 1e-5f);
  xn[t] = (v - mu) * rs * sc[t] + of[t];
  __syncthreads();
  float acc = 0.f;
#pragma unroll 8
  for (int k = 0; k < 256; ++k) acc += xn[k] * Wq[k*256 + t];
  q[row*256 + t] = acc * 0.0625f;          // * H^-0.5
  updates[row*256 + t] = 0.f;              // pre-zero for atomics
  if (t == 0) colsum[(row/11)*16 + (row%11)] = 0.f;
}

// ---------------- logits -> softmax(s) -> attn store + colsum atomics ------
// one wave per n; lane covers 4 h via ushort4/float4 loads
__global__ void k_attn(const u16* __restrict__ kv, const float* __restrict__ q,
                       float* __restrict__ attn, float* __restrict__ colsum) {
  __shared__ __align__(16) float ql[11*256];
  int t = threadIdx.x;
  int b = blockIdx.y;
  int n0 = blockIdx.x * 128;
  for (int i = t; i < 2816; i += 256) ql[i] = q[b*11*256 + i];
  __syncthreads();
  int lane = t & 63, wid = t >> 6;
  float cs[11];
#pragma unroll
  for (int s = 0; s < 11; ++s) cs[s] = 0.f;
  for (int i = 0; i < 32; ++i) {
    int n = n0 + wid*32 + i;
    size_t roff = ((size_t)b*4096 + n) * 512;
    ushort4 kraw = *(const ushort4*)(kv + roff + lane*4);
    float k0 = bf2f(kraw.x), k1 = bf2f(kraw.y), k2 = bf2f(kraw.z), k3 = bf2f(kraw.w);
    float p[11];
#pragma unroll
    for (int s = 0; s < 11; ++s) {
      float4 qv = *(const float4*)&ql[s*256 + lane*4];
      p[s] = k0*qv.x + k1*qv.y + k2*qv.z + k3*qv.w;
    }
#pragma unroll
    for (int s = 0; s < 11; ++s) {
#pragma unroll
      for (int off = 32; off; off >>= 1) p[s] += __shfl_xor(p[s], off);
    }
    float m = p[0];
#pragma unroll
    for (int s = 1; s < 11; ++s) m = fmaxf(m, p[s]);
    float Z = 0.f;
#pragma unroll
    for (int s = 0; s < 11; ++s) { p[s] = __expf(p[s] - m); Z += p[s]; }
    float iz = 1.f / Z;
#pragma unroll
    for (int s = 0; s < 11; ++s) { p[s] = p[s]*iz + 1e-8f; cs[s] += p[s]; }
    if (lane == 0) {
      size_t aoff = ((size_t)b*4096 + n) * 11;
#pragma unroll
      for (int s = 0; s < 11; ++s) attn[aoff + s] = p[s];
    }
  }
  if (lane == 0) {
#pragma unroll
    for (int s = 0; s < 11; ++s) atomicAdd(&colsum[b*16 + s], cs[s]);
  }
}

// ---------------- updates[b,s,h] = sum_n attn * vf (unnormalized) ----------
__global__ void k_updates(const u16* __restrict__ kv, const float* __restrict__ attn,
                          float* __restrict__ updates) {
  __shared__ float al[2816];
  int t = threadIdx.x;
  int b = blockIdx.y;
  int n0 = blockIdx.x * 256;
  size_t abase = ((size_t)b*4096 + n0) * 11;
  for (int i = t; i < 2816; i += 256) al[i] = attn[abase + i];
  __syncthreads();
  float acc[11];
#pragma unroll
  for (int s = 0; s < 11; ++s) acc[s] = 0.f;
  const u16* vp = kv + ((size_t)b*4096 + n0) * 512 + 256 + t;  // vf half
  for (int n = 0; n < 256; ++n) {
    float v = bf2f(vp[(size_t)n * 512]);
#pragma unroll
    for (int s = 0; s < 11; ++s) acc[s] += al[n*11 + s] * v;   // LDS broadcast
  }
#pragma unroll
  for (int s = 0; s < 11; ++s)
    atomicAdd(&updates[(b*11 + s)*256 + t], acc[s]);
}

// ---------------- gx = (updates / colsum) @ w_i ----------------------------
__global__ void k_gx(const float* __restrict__ updates, const float* __restrict__ colsum,
                     const float* __restrict__ wi, float* __restrict__ gx) {
  __shared__ float xn[256];
  int row = blockIdx.x, t = threadIdx.x;
  float inv = 1.f / colsum[(row/11)*16 + (row%11)];
  xn[t] = updates[row*256 + t] * inv;
  __syncthreads();
  float a0 = 0.f, a1 = 0.f, a2 = 0.f;
#pragma unroll 4
  for (int k = 0; k < 256; ++k) {
    float xv = xn[k];
    const float* wp = wi + k*768 + t;
    a0 += xv * wp[0];
    a1 += xv * wp[256];
    a2 += xv * wp[512];
  }
  gx[row*768 + t] = a0;
  gx[row*768 + 256 + t] = a1;
  gx[row*768 + 512 + t] = a2;
}

// ---------------- GRU over 11 slots as a sequence (h0 = 0) -----------------
__global__ void k_gru(const float* __restrict__ gx, const float* __restrict__ wh,
                      const float* __restrict__ gb, float* __restrict__ slots) {
  __shared__ float h[256], rh[256];
  int b = blockIdx.x, t = threadIdx.x;
  h[t] = 0.f;
  __syncthreads();
  for (int step = 0; step < 11; ++step) {
    int row = b*11 + step;
    float uz = gx[row*768 + t]       + gb[t];
    float ur = gx[row*768 + 256 + t] + gb[256 + t];
#pragma unroll 4
    for (int k = 0; k < 256; ++k) {
      float hk = h[k];
      uz += hk * wh[k*768 + t];
      ur += hk * wh[k*768 + 256 + t];
    }
    float z = 1.f / (1.f + __expf(-uz));
    float r = 1.f / (1.f + __expf(-ur));
    rh[t] = r * h[t];
    __syncthreads();                       // rh visible to all
    float ua = gx[row*768 + 512 + t] + gb[512 + t];
#pragma unroll 4
    for (int k = 0; k < 256; ++k) ua += rh[k] * wh[k*768 + 512 + t];
    float a  = tanhf(ua);
    float hn = (1.f - z)*h[t] + z*a;
    __syncthreads();                       // all rh reads done before h/rh rewrite
    h[t] = hn;
    slots[row*256 + t] = hn;
    __syncthreads();
  }
}

// ---------------- MLP: slots += relu(LN(slots)@w1+b1)@w2 + b2 --------------
__global__ void k_mlp(float* __restrict__ slots, const float* __restrict__ sc,
                      const float* __restrict__ of, const float* __restrict__ w1,
                      const float* __restrict__ b1, const float* __restrict__ w2,
                      const float* __restrict__ b2, float* __restrict__ out2) {
  __shared__ float xn[256];
  __shared__ float hid[512];
  __shared__ float red[8];
  int row = blockIdx.x, t = threadIdx.x;
  float v = slots[row*256 + t];
  float s1 = v, s2 = v*v;
#pragma unroll
  for (int off = 32; off; off >>= 1) { s1 += __shfl_xor(s1, off); s2 += __shfl_xor(s2, off); }
  int w = t >> 6;
  if ((t & 63) == 0) { red[w*2] = s1; red[w*2+1] = s2; }
  __syncthreads();
  float a1s = red[0] + red[2] + red[4] + red[6];
  float a2s = red[1] + red[3] + red[5] + red[7];
  float mu = a1s * (1.f/256.f);
  float rs = rsqrtf(a2s * (1.f/256.f) - mu*mu + 1e-5f);
  xn[t] = (v - mu) * rs * sc[t] + of[t];
  __syncthreads();
  float a0 = b1[t], a1 = b1[256 + t];
#pragma unroll 4
  for (int k = 0; k < 256; ++k) {
    float xv = xn[k];
    a0 += xv * w1[k*512 + t];
    a1 += xv * w1[k*512 + 256 + t];
  }
  hid[t]       = fmaxf(a0, 0.f);
  hid[256 + t] = fmaxf(a1, 0.f);
  __syncthreads();
  float o = v + b2[t];
#pragma unroll 4
  for (int k = 0; k < 512; ++k) o += hid[k] * w2[k*256 + t];
  slots[row*256 + t] = o;
  if (out2) out2[row*256 + t] = o;
}

extern "C" void kernel_launch(void* const* d_in, const int* in_sizes, int n_in,
                              void* d_out, int out_size, void* d_ws, size_t ws_size,
                              hipStream_t stream) {
  (void)in_sizes; (void)n_in; (void)out_size; (void)ws_size;
  const float* inputs = (const float*)d_in[0];
  const float* noise  = (const float*)d_in[1];
  const float* lnin_s = (const float*)d_in[2];
  const float* lnin_o = (const float*)d_in[3];
  const float* lnsl_s = (const float*)d_in[4];
  const float* lnsl_o = (const float*)d_in[5];
  const float* lnml_s = (const float*)d_in[6];
  const float* lnml_o = (const float*)d_in[7];
  const float* smu    = (const float*)d_in[8];
  const float* sls    = (const float*)d_in[9];
  const float* Wq     = (const float*)d_in[10];
  const float* Wk     = (const float*)d_in[11];
  const float* Wv     = (const float*)d_in[12];
  const float* gwi    = (const float*)d_in[13];
  const float* gwh    = (const float*)d_in[14];
  const float* gb     = (const float*)d_in[15];
  const float* w1     = (const float*)d_in[16];
  const float* b1     = (const float*)d_in[17];
  const float* w2     = (const float*)d_in[18];
  const float* b2     = (const float*)d_in[19];

  char* ws = (char*)d_ws;
  u16*    kv      = (u16*)(ws);                       // 131072 x 512 bf16 (kf|vf)   134217728 B
  u16*    wT      = (u16*)(ws + 134217728);           // 512 x 256 bf16 (Wkv^T)         262144 B
  float2* mu_rs   = (float2*)(ws + 134479872);        // 131072 x float2              1048576 B
  float*  slots   = (float*)(ws + 135528448);         // 352 x 256                     360448 B
  float*  q       = (float*)(ws + 135888896);         // 352 x 256                     360448 B
  float*  attn    = (float*)(ws + 136249344);         // 32 x 4096 x 11               5767168 B
  float*  colsum  = (float*)(ws + 142016512);         // 32 x 16                         2048 B
  float*  updates = (float*)(ws + 142018560);         // 352 x 256                     360448 B
  float*  gx      = (float*)(ws + 142379008);         // 352 x 768                    1081344 B

  k_stats     <<<32768, 256, 0, stream>>>(inputs, mu_rs);
  k_cvt_w     <<<512,   256, 0, stream>>>(Wk, Wv, wT);
  k_slots_init<<<352,   256, 0, stream>>>(noise, smu, sls, slots);
  k_gemm_kv   <<<dim3(4, 1024), 256, 0, stream>>>(inputs, mu_rs, lnin_s, lnin_o, wT, kv);

  for (int it = 0; it < 3; ++it) {
    k_q_ln    <<<352, 256, 0, stream>>>(slots, lnsl_s, lnsl_o, Wq, q, updates, colsum);
    k_attn    <<<dim3(32, 32), 256, 0, stream>>>(kv, q, attn, colsum);
    k_updates <<<dim3(16, 32), 256, 0, stream>>>(kv, attn, updates);
    k_gx      <<<352, 256, 0, stream>>>(updates, colsum, gwi, gx);
    k_gru     <<<32,  256, 0, stream>>>(gx, gwh, gb, slots);
    k_mlp     <<<352, 256, 0, stream>>>(slots, lnml_s, lnml_o, w1, b1, w2, b2,
                                        (it == 2) ? (float*)d_out : nullptr);
  }
}

// Round 3
// 1167.472 us; speedup vs baseline: 1.6329x; 1.6329x over previous
//
#include <hip/hip_runtime.h>

typedef unsigned short u16;
typedef __bf16 bf16x8 __attribute__((ext_vector_type(8)));
typedef float  f32x4  __attribute__((ext_vector_type(4)));
typedef unsigned short u16x8 __attribute__((ext_vector_type(8)));

#define NB 32
#define NN 4096
#define ND 256
#define NS 11
#define NH 256
#define NM 512

__device__ __forceinline__ u16 f2bf(float f) {
  unsigned u = __float_as_uint(f);
  u += 0x7FFF + ((u >> 16) & 1);      // RNE; inputs are finite
  return (u16)(u >> 16);
}
__device__ __forceinline__ float bf2f(u16 h) {
  return __uint_as_float(((unsigned)h) << 16);
}

// ---------------- per-row mean / rstd of inputs (one wave per row) ----------
__global__ void k_stats(const float* __restrict__ x, float2* __restrict__ mu_rs) {
  int lane = threadIdx.x & 63;
  int wid  = threadIdx.x >> 6;
  int row  = blockIdx.x * 4 + wid;
  float4 v = *(const float4*)(x + (size_t)row * 256 + lane * 4);
  float s1 = v.x + v.y + v.z + v.w;
  float s2 = v.x*v.x + v.y*v.y + v.z*v.z + v.w*v.w;
#pragma unroll
  for (int off = 32; off; off >>= 1) { s1 += __shfl_xor(s1, off); s2 += __shfl_xor(s2, off); }
  if (lane == 0) {
    float mu  = s1 * (1.f/256.f);
    float var = s2 * (1.f/256.f) - mu*mu;
    mu_rs[row] = make_float2(mu, rsqrtf(var + 1e-5f));
  }
}

// ---------------- Wk|Wv -> transposed bf16 wT[512][256] --------------------
__global__ void k_cvt_w(const float* __restrict__ Wk, const float* __restrict__ Wv,
                        u16* __restrict__ wT) {
  int c = blockIdx.x;           // output column 0..511
  int t = threadIdx.x;          // k 0..255
  const float* src = (c < 256) ? Wk : Wv;
  int cc = c & 255;
  wT[c * 256 + t] = f2bf(src[t * 256 + cc]);
}

// ---------------- convert all small-matmul weights to bf16 (row-major) -----
__global__ void k_cvt_all(const float* __restrict__ Wq, const float* __restrict__ wi,
                          const float* __restrict__ wh, const float* __restrict__ w1,
                          const float* __restrict__ w2, u16* __restrict__ wqb,
                          u16* __restrict__ wib, u16* __restrict__ whb,
                          u16* __restrict__ w1b, u16* __restrict__ w2b) {
  int idx = blockIdx.x * 256 + threadIdx.x;
  if      (idx < 65536)  wqb[idx]          = f2bf(Wq[idx]);
  else if (idx < 262144) wib[idx - 65536]  = f2bf(wi[idx - 65536]);
  else if (idx < 458752) whb[idx - 262144] = f2bf(wh[idx - 262144]);
  else if (idx < 589824) w1b[idx - 458752] = f2bf(w1[idx - 458752]);
  else                   w2b[idx - 589824] = f2bf(w2[idx - 589824]);
}

// ---------------- slots init ----------------------------------------------
__global__ void k_slots_init(const float* __restrict__ noise, const float* __restrict__ mu,
                             const float* __restrict__ ls, float* __restrict__ slots) {
  int row = blockIdx.x, t = threadIdx.x;
  slots[row*256 + t] = mu[t] + expf(ls[t]) * noise[row*256 + t];
}

// ---------------- fused LN + bf16 MFMA GEMM: kv = LN(x) @ [Wk|Wv] ----------
__global__ __launch_bounds__(256)
void k_gemm_kv(const float* __restrict__ x, const float2* __restrict__ mu_rs,
               const float* __restrict__ lnsc, const float* __restrict__ lnof,
               const u16* __restrict__ wT, u16* __restrict__ kv) {
  __shared__ __align__(16) u16 Al[128][72];
  __shared__ __align__(16) u16 Bl[128][72];
  __shared__ float scl[256], ofl[256];
  int t = threadIdx.x;
  scl[t] = lnsc[t]; ofl[t] = lnof[t];
  int row0 = blockIdx.y * 128;
  int col0 = blockIdx.x * 128;
  int srow = t >> 1, shalf = t & 1;
  float2 mr = mu_rs[row0 + srow];
  int lane = t & 63, w = t >> 6;
  int wm = (w & 1) * 64, wn = (w >> 1) * 64;
  int fr = lane & 15;
  int kq = (lane >> 4) * 8;
  f32x4 acc[4][4] = {};
  for (int kc = 0; kc < 256; kc += 64) {
    __syncthreads();
    {
      const float* xp = x + (size_t)(row0 + srow) * 256 + kc + shalf * 32;
#pragma unroll
      for (int g = 0; g < 4; ++g) {
        float4 f0 = *(const float4*)(xp + g*8);
        float4 f1 = *(const float4*)(xp + g*8 + 4);
        int kb = kc + shalf*32 + g*8;
        u16x8 o;
        o[0] = f2bf((f0.x - mr.x)*mr.y*scl[kb+0] + ofl[kb+0]);
        o[1] = f2bf((f0.y - mr.x)*mr.y*scl[kb+1] + ofl[kb+1]);
        o[2] = f2bf((f0.z - mr.x)*mr.y*scl[kb+2] + ofl[kb+2]);
        o[3] = f2bf((f0.w - mr.x)*mr.y*scl[kb+3] + ofl[kb+3]);
        o[4] = f2bf((f1.x - mr.x)*mr.y*scl[kb+4] + ofl[kb+4]);
        o[5] = f2bf((f1.y - mr.x)*mr.y*scl[kb+5] + ofl[kb+5]);
        o[6] = f2bf((f1.z - mr.x)*mr.y*scl[kb+6] + ofl[kb+6]);
        o[7] = f2bf((f1.w - mr.x)*mr.y*scl[kb+7] + ofl[kb+7]);
        *(u16x8*)&Al[srow][shalf*32 + g*8] = o;
      }
      const u16* wp = wT + (size_t)(col0 + srow) * 256 + kc + shalf*32;
#pragma unroll
      for (int g = 0; g < 4; ++g)
        *(u16x8*)&Bl[srow][shalf*32 + g*8] = *(const u16x8*)(wp + g*8);
    }
    __syncthreads();
#pragma unroll
    for (int ks = 0; ks < 2; ++ks) {
      int kk = ks*32 + kq;
      bf16x8 af[4], bfr[4];
#pragma unroll
      for (int i = 0; i < 4; ++i) af[i] = *(const bf16x8*)&Al[wm + i*16 + fr][kk];
#pragma unroll
      for (int i = 0; i < 4; ++i) bfr[i] = *(const bf16x8*)&Bl[wn + i*16 + fr][kk];
#pragma unroll
      for (int im = 0; im < 4; ++im)
#pragma unroll
        for (int in = 0; in < 4; ++in)
          acc[im][in] = __builtin_amdgcn_mfma_f32_16x16x32_bf16(af[im], bfr[in], acc[im][in], 0, 0, 0);
    }
  }
  int r4 = (lane >> 4) * 4;
#pragma unroll
  for (int im = 0; im < 4; ++im)
#pragma unroll
    for (int in = 0; in < 4; ++in) {
      int gcol = col0 + wn + in*16 + fr;
#pragma unroll
      for (int r = 0; r < 4; ++r) {
        int grow = row0 + wm + im*16 + r4 + r;
        kv[(size_t)grow * 512 + gcol] = f2bf(acc[im][in][r]);
      }
    }
}

// ---------------- q = LN(slots) @ Wq * H^-0.5 (k-split); zero updates ------
__global__ __launch_bounds__(256)
void k_q_ln(const float* __restrict__ slots, const float* __restrict__ sc,
            const float* __restrict__ of, const u16* __restrict__ wqb,
            float* __restrict__ q, float* __restrict__ updates,
            float* __restrict__ colsum) {
  __shared__ float xn[256];
  __shared__ float red[8];
  __shared__ float part[8][256];
  int row = blockIdx.x, t = threadIdx.x;
  float v = slots[row*256 + t];
  float s1 = v, s2 = v*v;
#pragma unroll
  for (int off = 32; off; off >>= 1) { s1 += __shfl_xor(s1, off); s2 += __shfl_xor(s2, off); }
  int w = t >> 6;
  if ((t & 63) == 0) { red[w*2] = s1; red[w*2+1] = s2; }
  __syncthreads();
  float a1 = red[0] + red[2] + red[4] + red[6];
  float a2 = red[1] + red[3] + red[5] + red[7];
  float mu = a1 * (1.f/256.f);
  float rs = rsqrtf(a2 * (1.f/256.f) - mu*mu + 1e-5f);
  xn[t] = (v - mu) * rs * sc[t] + of[t];
  updates[row*256 + t] = 0.f;
  if (t == 0) colsum[(row/11)*16 + (row%11)] = 0.f;
  __syncthreads();
  int tc = t & 31, kg = t >> 5;              // 8 k-groups x 32 k, 8 cols/thread
  float a[8] = {};
#pragma unroll 8
  for (int kk = 0; kk < 32; ++kk) {
    int k = kg*32 + kk;
    float xv = xn[k];
    u16x8 wv = *(const u16x8*)(wqb + k*256 + tc*8);
#pragma unroll
    for (int j = 0; j < 8; ++j) a[j] += xv * bf2f(wv[j]);
  }
  *(float4*)&part[kg][tc*8]     = make_float4(a[0], a[1], a[2], a[3]);
  *(float4*)&part[kg][tc*8 + 4] = make_float4(a[4], a[5], a[6], a[7]);
  __syncthreads();
  float s = 0.f;
#pragma unroll
  for (int g = 0; g < 8; ++g) s += part[g][t];
  q[row*256 + t] = s * 0.0625f;
}

// ---------------- logits -> softmax(s) -> attn store + colsum atomics ------
__global__ void k_attn(const u16* __restrict__ kv, const float* __restrict__ q,
                       float* __restrict__ attn, float* __restrict__ colsum) {
  __shared__ __align__(16) float ql[11*256];
  int t = threadIdx.x;
  int b = blockIdx.y;
  int n0 = blockIdx.x * 128;
  for (int i = t; i < 2816; i += 256) ql[i] = q[b*11*256 + i];
  __syncthreads();
  int lane = t & 63, wid = t >> 6;
  float cs[11];
#pragma unroll
  for (int s = 0; s < 11; ++s) cs[s] = 0.f;
  for (int i = 0; i < 32; ++i) {
    int n = n0 + wid*32 + i;
    size_t roff = ((size_t)b*4096 + n) * 512;
    ushort4 kraw = *(const ushort4*)(kv + roff + lane*4);
    float k0 = bf2f(kraw.x), k1 = bf2f(kraw.y), k2 = bf2f(kraw.z), k3 = bf2f(kraw.w);
    float p[11];
#pragma unroll
    for (int s = 0; s < 11; ++s) {
      float4 qv = *(const float4*)&ql[s*256 + lane*4];
      p[s] = k0*qv.x + k1*qv.y + k2*qv.z + k3*qv.w;
    }
#pragma unroll
    for (int s = 0; s < 11; ++s) {
#pragma unroll
      for (int off = 32; off; off >>= 1) p[s] += __shfl_xor(p[s], off);
    }
    float m = p[0];
#pragma unroll
    for (int s = 1; s < 11; ++s) m = fmaxf(m, p[s]);
    float Z = 0.f;
#pragma unroll
    for (int s = 0; s < 11; ++s) { p[s] = __expf(p[s] - m); Z += p[s]; }
    float iz = 1.f / Z;
#pragma unroll
    for (int s = 0; s < 11; ++s) { p[s] = p[s]*iz + 1e-8f; cs[s] += p[s]; }
    if (lane == 0) {
      size_t aoff = ((size_t)b*4096 + n) * 11;
#pragma unroll
      for (int s = 0; s < 11; ++s) attn[aoff + s] = p[s];
    }
  }
  if (lane == 0) {
#pragma unroll
    for (int s = 0; s < 11; ++s) atomicAdd(&colsum[b*16 + s], cs[s]);
  }
}

// ---------------- updates[b,s,h] = sum_n attn * vf (unnormalized) ----------
__global__ void k_updates(const u16* __restrict__ kv, const float* __restrict__ attn,
                          float* __restrict__ updates) {
  __shared__ float al[2816];
  int t = threadIdx.x;
  int b = blockIdx.y;
  int n0 = blockIdx.x * 256;
  size_t abase = ((size_t)b*4096 + n0) * 11;
  for (int i = t; i < 2816; i += 256) al[i] = attn[abase + i];
  __syncthreads();
  float acc[11];
#pragma unroll
  for (int s = 0; s < 11; ++s) acc[s] = 0.f;
  const u16* vp = kv + ((size_t)b*4096 + n0) * 512 + 256 + t;
  for (int n = 0; n < 256; ++n) {
    float v = bf2f(vp[(size_t)n * 512]);
#pragma unroll
    for (int s = 0; s < 11; ++s) acc[s] += al[n*11 + s] * v;
  }
#pragma unroll
  for (int s = 0; s < 11; ++s)
    atomicAdd(&updates[(b*11 + s)*256 + t], acc[s]);
}

// ---------------- gx = (updates / colsum) @ w_i  (k-split, block 384) ------
__global__ __launch_bounds__(384)
void k_gx(const float* __restrict__ updates, const float* __restrict__ colsum,
          const u16* __restrict__ wib, float* __restrict__ gx) {
  __shared__ float xn[256];
  __shared__ float part[4][768];
  int row = blockIdx.x, t = threadIdx.x;
  if (t < 256) {
    float inv = 1.f / colsum[(row/11)*16 + (row%11)];
    xn[t] = updates[row*256 + t] * inv;
  }
  __syncthreads();
  int tc = t % 96, kg = t / 96;              // 4 k-groups x 64 k, 8 cols/thread
  float a[8] = {};
#pragma unroll 4
  for (int kk = 0; kk < 64; ++kk) {
    int k = kg*64 + kk;
    float xv = xn[k];
    u16x8 wv = *(const u16x8*)(wib + k*768 + tc*8);
#pragma unroll
    for (int j = 0; j < 8; ++j) a[j] += xv * bf2f(wv[j]);
  }
  *(float4*)&part[kg][tc*8]     = make_float4(a[0], a[1], a[2], a[3]);
  *(float4*)&part[kg][tc*8 + 4] = make_float4(a[4], a[5], a[6], a[7]);
  __syncthreads();
#pragma unroll
  for (int c = t; c < 768; c += 384) {
    float s = part[0][c] + part[1][c] + part[2][c] + part[3][c];
    gx[row*768 + c] = s;
  }
}

// ---------------- GRU (block 512, k-split, bf16 wh) ------------------------
__global__ __launch_bounds__(512)
void k_gru(const float* __restrict__ gx, const u16* __restrict__ whb,
           const float* __restrict__ gb, float* __restrict__ slots) {
  __shared__ float h[256], rh[256], zv[256];
  __shared__ float part[4096];               // [8][512] phase1 / [16][256] phase2
  int b = blockIdx.x, t = threadIdx.x;
  if (t < 256) h[t] = 0.f;
  __syncthreads();
  for (int step = 0; step < 11; ++step) {
    int row = b*11 + step;
    { // phase1: uz, ur (cols 0..511 of wh)
      int tc = t & 63, kg = t >> 6;          // 8 k-groups x 32 k
      float a[8] = {};
#pragma unroll 8
      for (int kk = 0; kk < 32; ++kk) {
        int k = kg*32 + kk;
        float xv = h[k];
        u16x8 wv = *(const u16x8*)(whb + k*768 + tc*8);
#pragma unroll
        for (int j = 0; j < 8; ++j) a[j] += xv * bf2f(wv[j]);
      }
      *(float4*)&part[kg*512 + tc*8]     = make_float4(a[0], a[1], a[2], a[3]);
      *(float4*)&part[kg*512 + tc*8 + 4] = make_float4(a[4], a[5], a[6], a[7]);
    }
    __syncthreads();
    {
      int c = t;
      float s = gx[row*768 + c] + gb[c];
#pragma unroll
      for (int g = 0; g < 8; ++g) s += part[g*512 + c];
      float sg = 1.f / (1.f + __expf(-s));
      if (c < 256) zv[c] = sg;
      else         rh[c - 256] = sg * h[c - 256];
    }
    __syncthreads();
    { // phase2: ua (cols 512..767)
      int tc = t & 31, kg = t >> 5;          // 16 k-groups x 16 k
      float a[8] = {};
#pragma unroll 8
      for (int kk = 0; kk < 16; ++kk) {
        int k = kg*16 + kk;
        float xv = rh[k];
        u16x8 wv = *(const u16x8*)(whb + k*768 + 512 + tc*8);
#pragma unroll
        for (int j = 0; j < 8; ++j) a[j] += xv * bf2f(wv[j]);
      }
      *(float4*)&part[kg*256 + tc*8]     = make_float4(a[0], a[1], a[2], a[3]);
      *(float4*)&part[kg*256 + tc*8 + 4] = make_float4(a[4], a[5], a[6], a[7]);
    }
    __syncthreads();
    if (t < 256) {
      int c = t;
      float s = gx[row*768 + 512 + c] + gb[512 + c];
#pragma unroll
      for (int g = 0; g < 16; ++g) s += part[g*256 + c];
      float av = tanhf(s);
      float hn = (1.f - zv[c])*h[c] + zv[c]*av;
      h[c] = hn;
      slots[row*256 + c] = hn;
    }
    __syncthreads();
  }
}

// ---------------- MLP (k-split, bf16 w1/w2) --------------------------------
__global__ __launch_bounds__(256)
void k_mlp(float* __restrict__ slots, const float* __restrict__ sc,
           const float* __restrict__ of, const u16* __restrict__ w1b,
           const float* __restrict__ b1, const u16* __restrict__ w2b,
           const float* __restrict__ b2, float* __restrict__ out2) {
  __shared__ float xn[256];
  __shared__ float hid[512];
  __shared__ float red[8];
  __shared__ float part[2048];               // [4][512] phase1 / [8][256] phase2
  int row = blockIdx.x, t = threadIdx.x;
  float v = slots[row*256 + t];
  float s1 = v, s2 = v*v;
#pragma unroll
  for (int off = 32; off; off >>= 1) { s1 += __shfl_xor(s1, off); s2 += __shfl_xor(s2, off); }
  int w = t >> 6;
  if ((t & 63) == 0) { red[w*2] = s1; red[w*2+1] = s2; }
  __syncthreads();
  float a1s = red[0] + red[2] + red[4] + red[6];
  float a2s = red[1] + red[3] + red[5] + red[7];
  float mu = a1s * (1.f/256.f);
  float rs = rsqrtf(a2s * (1.f/256.f) - mu*mu + 1e-5f);
  xn[t] = (v - mu) * rs * sc[t] + of[t];
  __syncthreads();
  { // phase1: hid = relu(xn @ w1 + b1), C=512
    int tc = t & 63, kg = t >> 6;            // 4 k-groups x 64 k
    float a[8] = {};
#pragma unroll 4
    for (int kk = 0; kk < 64; ++kk) {
      int k = kg*64 + kk;
      float xv = xn[k];
      u16x8 wv = *(const u16x8*)(w1b + k*512 + tc*8);
#pragma unroll
      for (int j = 0; j < 8; ++j) a[j] += xv * bf2f(wv[j]);
    }
    *(float4*)&part[kg*512 + tc*8]     = make_float4(a[0], a[1], a[2], a[3]);
    *(float4*)&part[kg*512 + tc*8 + 4] = make_float4(a[4], a[5], a[6], a[7]);
  }
  __syncthreads();
#pragma unroll
  for (int c = t; c < 512; c += 256) {
    float s = b1[c];
#pragma unroll
    for (int g = 0; g < 4; ++g) s += part[g*512 + c];
    hid[c] = fmaxf(s, 0.f);
  }
  __syncthreads();
  { // phase2: out = hid @ w2, C=256, K=512
    int tc = t & 31, kg = t >> 5;            // 8 k-groups x 64 k
    float a[8] = {};
#pragma unroll 4
    for (int kk = 0; kk < 64; ++kk) {
      int k = kg*64 + kk;
      float xv = hid[k];
      u16x8 wv = *(const u16x8*)(w2b + k*256 + tc*8);
#pragma unroll
      for (int j = 0; j < 8; ++j) a[j] += xv * bf2f(wv[j]);
    }
    *(float4*)&part[kg*256 + tc*8]     = make_float4(a[0], a[1], a[2], a[3]);
    *(float4*)&part[kg*256 + tc*8 + 4] = make_float4(a[4], a[5], a[6], a[7]);
  }
  __syncthreads();
  {
    float s = v + b2[t];                     // residual (pre-LN slots value)
#pragma unroll
    for (int g = 0; g < 8; ++g) s += part[g*256 + t];
    slots[row*256 + t] = s;
    if (out2) out2[row*256 + t] = s;
  }
}

extern "C" void kernel_launch(void* const* d_in, const int* in_sizes, int n_in,
                              void* d_out, int out_size, void* d_ws, size_t ws_size,
                              hipStream_t stream) {
  (void)in_sizes; (void)n_in; (void)out_size; (void)ws_size;
  const float* inputs = (const float*)d_in[0];
  const float* noise  = (const float*)d_in[1];
  const float* lnin_s = (const float*)d_in[2];
  const float* lnin_o = (const float*)d_in[3];
  const float* lnsl_s = (const float*)d_in[4];
  const float* lnsl_o = (const float*)d_in[5];
  const float* lnml_s = (const float*)d_in[6];
  const float* lnml_o = (const float*)d_in[7];
  const float* smu    = (const float*)d_in[8];
  const float* sls    = (const float*)d_in[9];
  const float* Wq     = (const float*)d_in[10];
  const float* Wk     = (const float*)d_in[11];
  const float* Wv     = (const float*)d_in[12];
  const float* gwi    = (const float*)d_in[13];
  const float* gwh    = (const float*)d_in[14];
  const float* gb     = (const float*)d_in[15];
  const float* w1     = (const float*)d_in[16];
  const float* b1     = (const float*)d_in[17];
  const float* w2     = (const float*)d_in[18];
  const float* b2     = (const float*)d_in[19];

  // ---- workspace layout: high-water 143,230,976 B (round-1-proven arena) ----
  // kv:      [0, 134217728)
  // attn:    [134217728, 139984896)   (per-iter; k_attn -> k_updates)
  //   mu_rs aliases attn+0        (dead after k_gemm_kv, before first k_attn)
  //   wT    aliases attn+1048576  (dead after k_gemm_kv)
  // slots:   [139984896, 140345344)
  // updates: [140345344, 140705792)
  // gx:      [140705792, 141787136)   (k_gx -> k_gru)
  //   q aliases gx+0              (k_q_ln -> k_attn; dead before k_gx writes)
  // colsum:  [141787136, 141789184)
  // wqb/wib/whb/w1b/w2b: [141789184, 143230976)
  char* ws = (char*)d_ws;
  u16*    kv      = (u16*)(ws);
  float*  attn    = (float*)(ws + 134217728);
  float2* mu_rs   = (float2*)(ws + 134217728);
  u16*    wT      = (u16*)(ws + 134217728 + 1048576);
  float*  slots   = (float*)(ws + 139984896);
  float*  updates = (float*)(ws + 140345344);
  float*  gx      = (float*)(ws + 140705792);
  float*  q       = (float*)(ws + 140705792);
  float*  colsum  = (float*)(ws + 141787136);
  u16*    wqb     = (u16*)(ws + 141789184);
  u16*    wib     = (u16*)(ws + 141920256);
  u16*    whb     = (u16*)(ws + 142313472);
  u16*    w1b     = (u16*)(ws + 142706688);
  u16*    w2b     = (u16*)(ws + 142968832);

  k_stats     <<<32768, 256, 0, stream>>>(inputs, mu_rs);
  k_cvt_w     <<<512,   256, 0, stream>>>(Wk, Wv, wT);
  k_cvt_all   <<<2816,  256, 0, stream>>>(Wq, gwi, gwh, w1, w2, wqb, wib, whb, w1b, w2b);
  k_slots_init<<<352,   256, 0, stream>>>(noise, smu, sls, slots);
  k_gemm_kv   <<<dim3(4, 1024), 256, 0, stream>>>(inputs, mu_rs, lnin_s, lnin_o, wT, kv);

  for (int it = 0; it < 3; ++it) {
    k_q_ln    <<<352, 256, 0, stream>>>(slots, lnsl_s, lnsl_o, wqb, q, updates, colsum);
    k_attn    <<<dim3(32, 32), 256, 0, stream>>>(kv, q, attn, colsum);
    k_updates <<<dim3(16, 32), 256, 0, stream>>>(kv, attn, updates);
    k_gx      <<<352, 384, 0, stream>>>(updates, colsum, wib, gx);
    k_gru     <<<32,  512, 0, stream>>>(gx, whb, gb, slots);
    k_mlp     <<<352, 256, 0, stream>>>(slots, lnml_s, lnml_o, w1b, b1, w2b, b2,
                                        (it == 2) ? (float*)d_out : nullptr);
  }
}

// Round 4
// 664.418 us; speedup vs baseline: 2.8692x; 1.7571x over previous
//
#include <hip/hip_runtime.h>

typedef unsigned short u16;
typedef __bf16 bf16x8 __attribute__((ext_vector_type(8)));
typedef float  f32x4  __attribute__((ext_vector_type(4)));
typedef unsigned short u16x8 __attribute__((ext_vector_type(8)));

union U8cast { u16x8 u; bf16x8 b; };

#define NB 32
#define NN 4096
#define ND 256
#define NS 11
#define NH 256
#define NM 512

__device__ __forceinline__ u16 f2bf(float f) {
  unsigned u = __float_as_uint(f);
  u += 0x7FFF + ((u >> 16) & 1);      // RNE; inputs are finite
  return (u16)(u >> 16);
}
__device__ __forceinline__ float bf2f(u16 h) {
  return __uint_as_float(((unsigned)h) << 16);
}

// ---------------- per-row mean / rstd of inputs (one wave per row) ----------
__global__ void k_stats(const float* __restrict__ x, float2* __restrict__ mu_rs) {
  int lane = threadIdx.x & 63;
  int wid  = threadIdx.x >> 6;
  int row  = blockIdx.x * 4 + wid;
  float4 v = *(const float4*)(x + (size_t)row * 256 + lane * 4);
  float s1 = v.x + v.y + v.z + v.w;
  float s2 = v.x*v.x + v.y*v.y + v.z*v.z + v.w*v.w;
#pragma unroll
  for (int off = 32; off; off >>= 1) { s1 += __shfl_xor(s1, off); s2 += __shfl_xor(s2, off); }
  if (lane == 0) {
    float mu  = s1 * (1.f/256.f);
    float var = s2 * (1.f/256.f) - mu*mu;
    mu_rs[row] = make_float2(mu, rsqrtf(var + 1e-5f));
  }
}

// ---------------- Wk|Wv -> transposed bf16 wT[512][256] --------------------
__global__ void k_cvt_w(const float* __restrict__ Wk, const float* __restrict__ Wv,
                        u16* __restrict__ wT) {
  int c = blockIdx.x;
  int t = threadIdx.x;
  const float* src = (c < 256) ? Wk : Wv;
  int cc = c & 255;
  wT[c * 256 + t] = f2bf(src[t * 256 + cc]);
}

// ---------------- convert all small-matmul weights to bf16 -----------------
__global__ void k_cvt_all(const float* __restrict__ Wq, const float* __restrict__ wi,
                          const float* __restrict__ wh, const float* __restrict__ w1,
                          const float* __restrict__ w2, u16* __restrict__ wqb,
                          u16* __restrict__ wib, u16* __restrict__ whb,
                          u16* __restrict__ w1b, u16* __restrict__ w2b) {
  int idx = blockIdx.x * 256 + threadIdx.x;
  if      (idx < 65536)  wqb[idx]          = f2bf(Wq[idx]);
  else if (idx < 262144) wib[idx - 65536]  = f2bf(wi[idx - 65536]);
  else if (idx < 458752) whb[idx - 262144] = f2bf(wh[idx - 262144]);
  else if (idx < 589824) w1b[idx - 458752] = f2bf(w1[idx - 458752]);
  else                   w2b[idx - 589824] = f2bf(w2[idx - 589824]);
}

// ---------------- slots init ----------------------------------------------
__global__ void k_slots_init(const float* __restrict__ noise, const float* __restrict__ mu,
                             const float* __restrict__ ls, float* __restrict__ slots) {
  int row = blockIdx.x, t = threadIdx.x;
  slots[row*256 + t] = mu[t] + expf(ls[t]) * noise[row*256 + t];
}

// ---------------- fused LN + bf16 MFMA GEMM: kv = LN(x) @ [Wk|Wv] ----------
__global__ __launch_bounds__(256)
void k_gemm_kv(const float* __restrict__ x, const float2* __restrict__ mu_rs,
               const float* __restrict__ lnsc, const float* __restrict__ lnof,
               const u16* __restrict__ wT, u16* __restrict__ kv) {
  __shared__ __align__(16) u16 Al[128][72];
  __shared__ __align__(16) u16 Bl[128][72];
  __shared__ float scl[256], ofl[256];
  int t = threadIdx.x;
  scl[t] = lnsc[t]; ofl[t] = lnof[t];
  int row0 = blockIdx.y * 128;
  int col0 = blockIdx.x * 128;
  int srow = t >> 1, shalf = t & 1;
  float2 mr = mu_rs[row0 + srow];
  int lane = t & 63, w = t >> 6;
  int wm = (w & 1) * 64, wn = (w >> 1) * 64;
  int fr = lane & 15;
  int kq = (lane >> 4) * 8;
  f32x4 acc[4][4] = {};
  for (int kc = 0; kc < 256; kc += 64) {
    __syncthreads();
    {
      const float* xp = x + (size_t)(row0 + srow) * 256 + kc + shalf * 32;
#pragma unroll
      for (int g = 0; g < 4; ++g) {
        float4 f0 = *(const float4*)(xp + g*8);
        float4 f1 = *(const float4*)(xp + g*8 + 4);
        int kb = kc + shalf*32 + g*8;
        u16x8 o;
        o[0] = f2bf((f0.x - mr.x)*mr.y*scl[kb+0] + ofl[kb+0]);
        o[1] = f2bf((f0.y - mr.x)*mr.y*scl[kb+1] + ofl[kb+1]);
        o[2] = f2bf((f0.z - mr.x)*mr.y*scl[kb+2] + ofl[kb+2]);
        o[3] = f2bf((f0.w - mr.x)*mr.y*scl[kb+3] + ofl[kb+3]);
        o[4] = f2bf((f1.x - mr.x)*mr.y*scl[kb+4] + ofl[kb+4]);
        o[5] = f2bf((f1.y - mr.x)*mr.y*scl[kb+5] + ofl[kb+5]);
        o[6] = f2bf((f1.z - mr.x)*mr.y*scl[kb+6] + ofl[kb+6]);
        o[7] = f2bf((f1.w - mr.x)*mr.y*scl[kb+7] + ofl[kb+7]);
        *(u16x8*)&Al[srow][shalf*32 + g*8] = o;
      }
      const u16* wp = wT + (size_t)(col0 + srow) * 256 + kc + shalf*32;
#pragma unroll
      for (int g = 0; g < 4; ++g)
        *(u16x8*)&Bl[srow][shalf*32 + g*8] = *(const u16x8*)(wp + g*8);
    }
    __syncthreads();
#pragma unroll
    for (int ks = 0; ks < 2; ++ks) {
      int kk = ks*32 + kq;
      bf16x8 af[4], bfr[4];
#pragma unroll
      for (int i = 0; i < 4; ++i) af[i] = *(const bf16x8*)&Al[wm + i*16 + fr][kk];
#pragma unroll
      for (int i = 0; i < 4; ++i) bfr[i] = *(const bf16x8*)&Bl[wn + i*16 + fr][kk];
#pragma unroll
      for (int im = 0; im < 4; ++im)
#pragma unroll
        for (int in = 0; in < 4; ++in)
          acc[im][in] = __builtin_amdgcn_mfma_f32_16x16x32_bf16(af[im], bfr[in], acc[im][in], 0, 0, 0);
    }
  }
  int r4 = (lane >> 4) * 4;
#pragma unroll
  for (int im = 0; im < 4; ++im)
#pragma unroll
    for (int in = 0; in < 4; ++in) {
      int gcol = col0 + wn + in*16 + fr;
#pragma unroll
      for (int r = 0; r < 4; ++r) {
        int grow = row0 + wm + im*16 + r4 + r;
        kv[(size_t)grow * 512 + gcol] = f2bf(acc[im][in][r]);
      }
    }
}

// ---------------- q = LN(slots) @ Wq * H^-0.5 (k-split); zero updates ------
__global__ __launch_bounds__(256)
void k_q_ln(const float* __restrict__ slots, const float* __restrict__ sc,
            const float* __restrict__ of, const u16* __restrict__ wqb,
            float* __restrict__ q, float* __restrict__ updates,
            float* __restrict__ colsum) {
  __shared__ float xn[256];
  __shared__ float red[8];
  __shared__ float part[8][256];
  int row = blockIdx.x, t = threadIdx.x;
  float v = slots[row*256 + t];
  float s1 = v, s2 = v*v;
#pragma unroll
  for (int off = 32; off; off >>= 1) { s1 += __shfl_xor(s1, off); s2 += __shfl_xor(s2, off); }
  int w = t >> 6;
  if ((t & 63) == 0) { red[w*2] = s1; red[w*2+1] = s2; }
  __syncthreads();
  float a1 = red[0] + red[2] + red[4] + red[6];
  float a2 = red[1] + red[3] + red[5] + red[7];
  float mu = a1 * (1.f/256.f);
  float rs = rsqrtf(a2 * (1.f/256.f) - mu*mu + 1e-5f);
  xn[t] = (v - mu) * rs * sc[t] + of[t];
  updates[row*256 + t] = 0.f;
  if (t == 0) colsum[(row/11)*16 + (row%11)] = 0.f;
  __syncthreads();
  int tc = t & 31, kg = t >> 5;
  float a[8] = {};
#pragma unroll 8
  for (int kk = 0; kk < 32; ++kk) {
    int k = kg*32 + kk;
    float xv = xn[k];
    u16x8 wv = *(const u16x8*)(wqb + k*256 + tc*8);
#pragma unroll
    for (int j = 0; j < 8; ++j) a[j] += xv * bf2f(wv[j]);
  }
  *(float4*)&part[kg][tc*8]     = make_float4(a[0], a[1], a[2], a[3]);
  *(float4*)&part[kg][tc*8 + 4] = make_float4(a[4], a[5], a[6], a[7]);
  __syncthreads();
  float s = 0.f;
#pragma unroll
  for (int g = 0; g < 8; ++g) s += part[g][t];
  q[row*256 + t] = s * 0.0625f;
}

// ---------------- FUSED attn: logits->softmax->P, updates += P^T @ vf ------
// grid (16 n-blocks, 32 b), 256 thr. Per block: 256 n as 4 chunks of 64.
// logits GEMM: A=kf[64x256], B=q^T[16x256] (rows contiguous), MFMA 16x16x32.
// softmax per-n in-thread (wave 0). updates GEMM: A=P^T[16x64], B=vf[64x256],
// acc in regs across chunks, one atomic pass at end. No attn global buffer.
__global__ __launch_bounds__(256)
void k_attn_up(const u16* __restrict__ kv, const float* __restrict__ qg,
               float* __restrict__ updates, float* __restrict__ colsum) {
  __shared__ __align__(16) u16 kfL[64][264];   // pad: A-frag reads spread banks
  __shared__ __align__(16) u16 vfL[64][256];   // chunk-swizzled: col = h ^ (((n>>3)&3)*16)
  __shared__ __align__(16) u16 qTL[16][264];   // q^T bf16, s>=11 rows zero
  __shared__ __align__(16) u16 PTL[16][72];    // P^T bf16 (A-operand layout)
  __shared__ float Lg[64][17];                 // logits scratch (pad 16->17)
  int t = threadIdx.x;
  int b = blockIdx.y;
  int nb0 = blockIdx.x * 256;
  int lane = t & 63, w = t >> 6;
  int fr = lane & 15, kq = lane >> 4;

  // stage q^T (bf16) + zero PT
#pragma unroll
  for (int i = t; i < 512; i += 256) {         // 16 rows x 32 chunks of 8
    int s = i >> 5, k0 = (i & 31) * 8;
    u16x8 o;
    if (s < 11) {
      const float* qp = qg + (size_t)b*2816 + s*256 + k0;
#pragma unroll
      for (int j = 0; j < 8; ++j) o[j] = f2bf(qp[j]);
    } else {
#pragma unroll
      for (int j = 0; j < 8; ++j) o[j] = 0;
    }
    *(u16x8*)&qTL[s][k0] = o;
  }
  for (int i = t; i < 16*72; i += 256) ((u16*)PTL)[i] = 0;

  f32x4 accU[4] = {};                          // updates acc: 4 h-tiles x (16s x 16h)
  float csA[11];
#pragma unroll
  for (int s = 0; s < 11; ++s) csA[s] = 0.f;

  for (int c = 0; c < 4; ++c) {
    int n0 = nb0 + c*64;
    __syncthreads();                           // prev chunk LDS reads done / qT ready
    // ---- stage kv chunk: 64 n x (256 kf | 256 vf), coalesced 16B ----
    {
      int hc = (t & 31) * 8;                   // 8-col chunk
      int swz_h = hc ^ ((c & 3) == (c & 3) ? 0 : 0); // (placeholder keeps hc)
#pragma unroll
      for (int nr = 0; nr < 8; ++nr) {
        int n = nr*8 + (t >> 5);
        size_t base = ((size_t)b*4096 + n0 + n) * 512;
        u16x8 kvk = *(const u16x8*)(kv + base + hc);
        *(u16x8*)&kfL[n][hc] = kvk;
        u16x8 kvv = *(const u16x8*)(kv + base + 256 + hc);
        *(u16x8*)&vfL[n][hc ^ (((n >> 3) & 3) * 16)] = kvv;
      }
    }
    __syncthreads();
    // ---- logits MFMA: wave w handles n-tile [w*16, w*16+16) ----
    {
      f32x4 aL = {};
#pragma unroll
      for (int kc = 0; kc < 256; kc += 32) {
        bf16x8 af = *(const bf16x8*)&kfL[w*16 + fr][kc + kq*8];
        bf16x8 bq = *(const bf16x8*)&qTL[fr][kc + kq*8];
        aL = __builtin_amdgcn_mfma_f32_16x16x32_bf16(af, bq, aL, 0, 0, 0);
      }
#pragma unroll
      for (int r = 0; r < 4; ++r)
        Lg[w*16 + kq*4 + r][fr] = aL[r];
    }
    __syncthreads();
    // ---- softmax per n, in-thread (wave 0 only) ----
    if (t < 64) {
      float p[11];
#pragma unroll
      for (int s = 0; s < 11; ++s) p[s] = Lg[t][s];
      float m = p[0];
#pragma unroll
      for (int s = 1; s < 11; ++s) m = fmaxf(m, p[s]);
      float Z = 0.f;
#pragma unroll
      for (int s = 0; s < 11; ++s) { p[s] = __expf(p[s] - m); Z += p[s]; }
      float iz = 1.f / Z;
#pragma unroll
      for (int s = 0; s < 11; ++s) {
        u16 pb = f2bf(p[s]*iz + 1e-8f);
        csA[s] += bf2f(pb);                    // colsum of the rounded P
        PTL[s][t] = pb;
      }
    }
    __syncthreads();
    // ---- updates MFMA: wave w handles h in [w*64, w*64+64), K=64(n) ----
#pragma unroll
    for (int ht = 0; ht < 4; ++ht) {
      int h = w*64 + ht*16 + fr;
#pragma unroll
      for (int kc = 0; kc < 64; kc += 32) {
        bf16x8 aP = *(const bf16x8*)&PTL[fr][kc + kq*8];
        U8cast bv;
#pragma unroll
        for (int j = 0; j < 8; ++j) {
          int k = kc + kq*8 + j;
          bv.u[j] = vfL[k][h ^ (((k >> 3) & 3) * 16)];
        }
        accU[ht] = __builtin_amdgcn_mfma_f32_16x16x32_bf16(aP, bv.b, accU[ht], 0, 0, 0);
      }
    }
  }
  // ---- flush updates (C: row=s=kq*4+r, col=h) ----
#pragma unroll
  for (int ht = 0; ht < 4; ++ht) {
    int h = w*64 + ht*16 + fr;
#pragma unroll
    for (int r = 0; r < 4; ++r) {
      int s = kq*4 + r;
      if (s < 11)
        atomicAdd(&updates[((size_t)b*11 + s)*256 + h], accU[ht][r]);
    }
  }
  // ---- colsum reduce (wave 0) ----
  if (t < 64) {
#pragma unroll
    for (int s = 0; s < 11; ++s) {
#pragma unroll
      for (int off = 32; off; off >>= 1) csA[s] += __shfl_xor(csA[s], off);
    }
    if (lane == 0) {
#pragma unroll
      for (int s = 0; s < 11; ++s) atomicAdd(&colsum[b*16 + s], csA[s]);
    }
  }
}

// ---------------- gx = (updates / colsum) @ w_i  (k-split, block 384) ------
__global__ __launch_bounds__(384)
void k_gx(const float* __restrict__ updates, const float* __restrict__ colsum,
          const u16* __restrict__ wib, float* __restrict__ gx) {
  __shared__ float xn[256];
  __shared__ float part[4][768];
  int row = blockIdx.x, t = threadIdx.x;
  if (t < 256) {
    float inv = 1.f / colsum[(row/11)*16 + (row%11)];
    xn[t] = updates[row*256 + t] * inv;
  }
  __syncthreads();
  int tc = t % 96, kg = t / 96;
  float a[8] = {};
#pragma unroll 4
  for (int kk = 0; kk < 64; ++kk) {
    int k = kg*64 + kk;
    float xv = xn[k];
    u16x8 wv = *(const u16x8*)(wib + k*768 + tc*8);
#pragma unroll
    for (int j = 0; j < 8; ++j) a[j] += xv * bf2f(wv[j]);
  }
  *(float4*)&part[kg][tc*8]     = make_float4(a[0], a[1], a[2], a[3]);
  *(float4*)&part[kg][tc*8 + 4] = make_float4(a[4], a[5], a[6], a[7]);
  __syncthreads();
#pragma unroll
  for (int c = t; c < 768; c += 384) {
    float s = part[0][c] + part[1][c] + part[2][c] + part[3][c];
    gx[row*768 + c] = s;
  }
}

// ---------------- GRU (block 512, k-split, bf16 wh) ------------------------
__global__ __launch_bounds__(512)
void k_gru(const float* __restrict__ gx, const u16* __restrict__ whb,
           const float* __restrict__ gb, float* __restrict__ slots) {
  __shared__ float h[256], rh[256], zv[256];
  __shared__ float part[4096];
  int b = blockIdx.x, t = threadIdx.x;
  if (t < 256) h[t] = 0.f;
  __syncthreads();
  for (int step = 0; step < 11; ++step) {
    int row = b*11 + step;
    {
      int tc = t & 63, kg = t >> 6;
      float a[8] = {};
#pragma unroll 8
      for (int kk = 0; kk < 32; ++kk) {
        int k = kg*32 + kk;
        float xv = h[k];
        u16x8 wv = *(const u16x8*)(whb + k*768 + tc*8);
#pragma unroll
        for (int j = 0; j < 8; ++j) a[j] += xv * bf2f(wv[j]);
      }
      *(float4*)&part[kg*512 + tc*8]     = make_float4(a[0], a[1], a[2], a[3]);
      *(float4*)&part[kg*512 + tc*8 + 4] = make_float4(a[4], a[5], a[6], a[7]);
    }
    __syncthreads();
    {
      int c = t;
      float s = gx[row*768 + c] + gb[c];
#pragma unroll
      for (int g = 0; g < 8; ++g) s += part[g*512 + c];
      float sg = 1.f / (1.f + __expf(-s));
      if (c < 256) zv[c] = sg;
      else         rh[c - 256] = sg * h[c - 256];
    }
    __syncthreads();
    {
      int tc = t & 31, kg = t >> 5;
      float a[8] = {};
#pragma unroll 8
      for (int kk = 0; kk < 16; ++kk) {
        int k = kg*16 + kk;
        float xv = rh[k];
        u16x8 wv = *(const u16x8*)(whb + k*768 + 512 + tc*8);
#pragma unroll
        for (int j = 0; j < 8; ++j) a[j] += xv * bf2f(wv[j]);
      }
      *(float4*)&part[kg*256 + tc*8]     = make_float4(a[0], a[1], a[2], a[3]);
      *(float4*)&part[kg*256 + tc*8 + 4] = make_float4(a[4], a[5], a[6], a[7]);
    }
    __syncthreads();
    if (t < 256) {
      int c = t;
      float s = gx[row*768 + 512 + c] + gb[512 + c];
#pragma unroll
      for (int g = 0; g < 16; ++g) s += part[g*256 + c];
      float av = tanhf(s);
      float hn = (1.f - zv[c])*h[c] + zv[c]*av;
      h[c] = hn;
      slots[row*256 + c] = hn;
    }
    __syncthreads();
  }
}

// ---------------- MLP (k-split, bf16 w1/w2) --------------------------------
__global__ __launch_bounds__(256)
void k_mlp(float* __restrict__ slots, const float* __restrict__ sc,
           const float* __restrict__ of, const u16* __restrict__ w1b,
           const float* __restrict__ b1, const u16* __restrict__ w2b,
           const float* __restrict__ b2, float* __restrict__ out2) {
  __shared__ float xn[256];
  __shared__ float hid[512];
  __shared__ float red[8];
  __shared__ float part[2048];
  int row = blockIdx.x, t = threadIdx.x;
  float v = slots[row*256 + t];
  float s1 = v, s2 = v*v;
#pragma unroll
  for (int off = 32; off; off >>= 1) { s1 += __shfl_xor(s1, off); s2 += __shfl_xor(s2, off); }
  int w = t >> 6;
  if ((t & 63) == 0) { red[w*2] = s1; red[w*2+1] = s2; }
  __syncthreads();
  float a1s = red[0] + red[2] + red[4] + red[6];
  float a2s = red[1] + red[3] + red[5] + red[7];
  float mu = a1s * (1.f/256.f);
  float rs = rsqrtf(a2s * (1.f/256.f) - mu*mu + 1e-5f);
  xn[t] = (v - mu) * rs * sc[t] + of[t];
  __syncthreads();
  {
    int tc = t & 63, kg = t >> 6;
    float a[8] = {};
#pragma unroll 4
    for (int kk = 0; kk < 64; ++kk) {
      int k = kg*64 + kk;
      float xv = xn[k];
      u16x8 wv = *(const u16x8*)(w1b + k*512 + tc*8);
#pragma unroll
      for (int j = 0; j < 8; ++j) a[j] += xv * bf2f(wv[j]);
    }
    *(float4*)&part[kg*512 + tc*8]     = make_float4(a[0], a[1], a[2], a[3]);
    *(float4*)&part[kg*512 + tc*8 + 4] = make_float4(a[4], a[5], a[6], a[7]);
  }
  __syncthreads();
#pragma unroll
  for (int c = t; c < 512; c += 256) {
    float s = b1[c];
#pragma unroll
    for (int g = 0; g < 4; ++g) s += part[g*512 + c];
    hid[c] = fmaxf(s, 0.f);
  }
  __syncthreads();
  {
    int tc = t & 31, kg = t >> 5;
    float a[8] = {};
#pragma unroll 4
    for (int kk = 0; kk < 64; ++kk) {
      int k = kg*64 + kk;
      float xv = hid[k];
      u16x8 wv = *(const u16x8*)(w2b + k*256 + tc*8);
#pragma unroll
      for (int j = 0; j < 8; ++j) a[j] += xv * bf2f(wv[j]);
    }
    *(float4*)&part[kg*256 + tc*8]     = make_float4(a[0], a[1], a[2], a[3]);
    *(float4*)&part[kg*256 + tc*8 + 4] = make_float4(a[4], a[5], a[6], a[7]);
  }
  __syncthreads();
  {
    float s = v + b2[t];
#pragma unroll
    for (int g = 0; g < 8; ++g) s += part[g*256 + t];
    slots[row*256 + t] = s;
    if (out2) out2[row*256 + t] = s;
  }
}

extern "C" void kernel_launch(void* const* d_in, const int* in_sizes, int n_in,
                              void* d_out, int out_size, void* d_ws, size_t ws_size,
                              hipStream_t stream) {
  (void)in_sizes; (void)n_in; (void)out_size; (void)ws_size;
  const float* inputs = (const float*)d_in[0];
  const float* noise  = (const float*)d_in[1];
  const float* lnin_s = (const float*)d_in[2];
  const float* lnin_o = (const float*)d_in[3];
  const float* lnsl_s = (const float*)d_in[4];
  const float* lnsl_o = (const float*)d_in[5];
  const float* lnml_s = (const float*)d_in[6];
  const float* lnml_o = (const float*)d_in[7];
  const float* smu    = (const float*)d_in[8];
  const float* sls    = (const float*)d_in[9];
  const float* Wq     = (const float*)d_in[10];
  const float* Wk     = (const float*)d_in[11];
  const float* Wv     = (const float*)d_in[12];
  const float* gwi    = (const float*)d_in[13];
  const float* gwh    = (const float*)d_in[14];
  const float* gb     = (const float*)d_in[15];
  const float* w1     = (const float*)d_in[16];
  const float* b1     = (const float*)d_in[17];
  const float* w2     = (const float*)d_in[18];
  const float* b2     = (const float*)d_in[19];

  // ---- workspace layout: high-water 143,230,976 B (round-3-proven arena) ----
  char* ws = (char*)d_ws;
  u16*    kv      = (u16*)(ws);
  float2* mu_rs   = (float2*)(ws + 134217728);           // scratch region (ex-attn)
  u16*    wT      = (u16*)(ws + 134217728 + 1048576);
  float*  slots   = (float*)(ws + 139984896);
  float*  updates = (float*)(ws + 140345344);
  float*  gx      = (float*)(ws + 140705792);
  float*  q       = (float*)(ws + 140705792);            // aliases gx (q dead before k_gx)
  float*  colsum  = (float*)(ws + 141787136);
  u16*    wqb     = (u16*)(ws + 141789184);
  u16*    wib     = (u16*)(ws + 141920256);
  u16*    whb     = (u16*)(ws + 142313472);
  u16*    w1b     = (u16*)(ws + 142706688);
  u16*    w2b     = (u16*)(ws + 142968832);

  k_stats     <<<32768, 256, 0, stream>>>(inputs, mu_rs);
  k_cvt_w     <<<512,   256, 0, stream>>>(Wk, Wv, wT);
  k_cvt_all   <<<2816,  256, 0, stream>>>(Wq, gwi, gwh, w1, w2, wqb, wib, whb, w1b, w2b);
  k_slots_init<<<352,   256, 0, stream>>>(noise, smu, sls, slots);
  k_gemm_kv   <<<dim3(4, 1024), 256, 0, stream>>>(inputs, mu_rs, lnin_s, lnin_o, wT, kv);

  for (int it = 0; it < 3; ++it) {
    k_q_ln    <<<352, 256, 0, stream>>>(slots, lnsl_s, lnsl_o, wqb, q, updates, colsum);
    k_attn_up <<<dim3(16, 32), 256, 0, stream>>>(kv, q, updates, colsum);
    k_gx      <<<352, 384, 0, stream>>>(updates, colsum, wib, gx);
    k_gru     <<<32,  512, 0, stream>>>(gx, whb, gb, slots);
    k_mlp     <<<352, 256, 0, stream>>>(slots, lnml_s, lnml_o, w1b, b1, w2b, b2,
                                        (it == 2) ? (float*)d_out : nullptr);
  }
}